// Round 10
// baseline (137.457 us; speedup 1.0000x reference)
//
#include <hip/hip_runtime.h>
#include <math.h>

// Fused flash attention, B=64, L=1024, D=64, fp32 in/out.
// out = softmax(mask(Q K^T / 8)) V ; key >= valid_len[b] -> -1e6 -> exp == 0 exactly,
// so KV tiles >= valid are skipped (exact). exp2 domain, QSCALE folded into Q.
// Swapped-operand QK^T (st = mfma(A=K, B=Q)): lane ln owns q-row ln.
// sigma key-permutation (K LDS rows at sigma(kr), bits[5:4]<->[3:2]) makes each
// lane's 16 P-values contiguous -> P-store = 2x ds_write_b128, conflict-free.
// Length-stratified block scrambling (633*i mod 1024 over LPT-sorted batches)
// balances per-CU work (block cost ~ valid_len[b]).

typedef __attribute__((ext_vector_type(4))) float f32x4;
typedef __attribute__((ext_vector_type(8))) short bf16x8;
typedef __attribute__((ext_vector_type(8))) unsigned short u16x8;

constexpr int Bn = 64, Ln = 1024, Dn = 64;
constexpr float QSCALE = 0.125f * 1.44269504088896340736f;  // 1/sqrt(64) * log2(e)
constexpr float DEFER_THR = 10.0f;   // log2 domain: deferred p bounded by 2^10

__device__ inline unsigned short f2bf(float x) {  // round-to-nearest-even
    unsigned int u = __float_as_uint(x);
    return (unsigned short)((u + 0x7fffu + ((u >> 16) & 1u)) >> 16);
}

__global__ __launch_bounds__(256) void flash_attn(
    const float* __restrict__ Q, const float* __restrict__ K,
    const float* __restrict__ V, const int* __restrict__ VL,
    float* __restrict__ O)
{
    __shared__ unsigned short kls[2][64 * 64];   // K tile [sigma(kv)][d] bf16, XOR-swizzled
    __shared__ unsigned short vls[2][64 * 64];   // V tile [d][kv] bf16, XOR-swizzled
    __shared__ unsigned short plds[4][16 * 64];  // per-wave P [q][k^], XOR-swizzled
    __shared__ int order_s[64];                  // LPT: order_s[r] = batch with r-th largest valid

    const int tid = threadIdx.x;
    const int w = tid >> 6, l = tid & 63;
    const int lg = l >> 4, ln = l & 15;

    // ---- LPT rank table (once per block; 64 batches == 64 lanes) ----
    {
        const int vme = VL[l];
        int rank = 0;
        for (int i = 0; i < 64; ++i) {
            const int vi = __shfl(vme, i, 64);
            rank += (vi > vme) || (vi == vme && i < l);
        }
        if (w == 0) order_s[rank] = l;
    }
    __syncthreads();

    // ---- scrambled item: stratify block lengths across any CU-assignment stride ----
    const int r = (633 * blockIdx.x) & 1023;     // gcd(633,1024)=1 -> bijection
    const int b = order_s[r >> 4];
    const int qt = r & 15;
    const int qbase = qt * 64 + w * 16;
    const int valid = VL[b];
    const int nkt = (valid + 63) >> 6;           // tiles beyond valid contribute exactly 0

    const float* Kbase = K + (size_t)b * Ln * Dn;
    const float* Vbase = V + (size_t)b * Ln * Dn;

    // ---- Q B-fragments (swapped-QK) ----
    bf16x8 bq0, bq1;
    {
        const f32x4* qp = reinterpret_cast<const f32x4*>(Q + ((size_t)b * Ln + qbase + ln) * Dn);
        f32x4 q0 = qp[lg * 2], q1 = qp[lg * 2 + 1], q2 = qp[8 + lg * 2], q3 = qp[8 + lg * 2 + 1];
        #pragma unroll
        for (int j = 0; j < 4; ++j) {
            bq0[j]     = (short)f2bf(q0[j] * QSCALE);
            bq0[j + 4] = (short)f2bf(q1[j] * QSCALE);
            bq1[j]     = (short)f2bf(q2[j] * QSCALE);
            bq1[j + 4] = (short)f2bf(q3[j] * QSCALE);
        }
    }

    // staging thread mapping
    const int kr = tid >> 2, kc = (tid & 3) * 16;  // K: global row kr, cols kc..kc+15
    const int sr = ((kr & 0xC) << 2) | ((kr >> 2) & 0xC) | (kr & 3);  // sigma(kr)
    const int vd = l, vk0 = w * 16;                // V: d = lane, k = vk0..vk0+15

    f32x4 kpre[4];
    float vpre[16];

    char* const kls0 = reinterpret_cast<char*>(kls[0]);
    char* const kls1 = reinterpret_cast<char*>(kls[1]);
    char* const vls0 = reinterpret_cast<char*>(vls[0]);
    char* const vls1 = reinterpret_cast<char*>(vls[1]);
    char* const pwb  = reinterpret_cast<char*>(plds[w]);

    const int kb = sr * 128 + kc * 2, ksw = (sr & 7) << 4;
    const int vb = vd * 128 + vk0 * 2, vsw = (vd & 7) << 4;
    const int psw = (ln & 7) << 4;

    // stage helper: convert kpre/vpre -> bf16, write into buffer pbuf
    auto stage_write = [&](int pbuf) {
        char* kd = pbuf ? kls1 : kls0;
        char* vdst = pbuf ? vls1 : vls0;
        u16x8 c0, c1;
        #pragma unroll
        for (int j = 0; j < 4; ++j) {
            c0[j]     = f2bf(kpre[0][j]);  c0[j + 4] = f2bf(kpre[1][j]);
            c1[j]     = f2bf(kpre[2][j]);  c1[j + 4] = f2bf(kpre[3][j]);
        }
        *reinterpret_cast<u16x8*>(kd + ((kb)      ^ ksw)) = c0;
        *reinterpret_cast<u16x8*>(kd + ((kb + 16) ^ ksw)) = c1;
        u16x8 v0, v1;
        #pragma unroll
        for (int j = 0; j < 8; ++j) { v0[j] = f2bf(vpre[j]); v1[j] = f2bf(vpre[j + 8]); }
        *reinterpret_cast<u16x8*>(vdst + ((vb)      ^ vsw)) = v0;
        *reinterpret_cast<u16x8*>(vdst + ((vb + 16) ^ vsw)) = v1;
    };

    // ---- prologue: tile 0 -> buf 0 ----
    {
        const f32x4* kp = reinterpret_cast<const f32x4*>(Kbase + (size_t)kr * Dn + kc);
        #pragma unroll
        for (int i = 0; i < 4; ++i) kpre[i] = kp[i];
        const float* vp = Vbase + (size_t)vk0 * Dn + vd;
        #pragma unroll
        for (int i = 0; i < 16; ++i) vpre[i] = vp[(size_t)i * Dn];
    }
    stage_write(0);
    __syncthreads();

    f32x4 acc[4] = {{0.f,0.f,0.f,0.f},{0.f,0.f,0.f,0.f},{0.f,0.f,0.f,0.f},{0.f,0.f,0.f,0.f}};
    float mrow = -1e30f;   // running max for q = ln (replicated over the 4 lane-groups)
    float lrow = 0.f;

    int p = 0;
    for (int kt = 0; kt < nkt; ++kt, p ^= 1) {
        const bool has_next = (kt + 1 < nkt);
        char* kcur = p ? kls1 : kls0;
        char* vcur = p ? vls1 : vls0;

        // ---- issue next tile's global loads (consumed by stage_write below) ----
        if (has_next) {
            const f32x4* kp = reinterpret_cast<const f32x4*>(Kbase + (size_t)((kt + 1) * 64 + kr) * Dn + kc);
            #pragma unroll
            for (int i = 0; i < 4; ++i) kpre[i] = kp[i];
            const float* vp = Vbase + (size_t)((kt + 1) * 64 + vk0) * Dn + vd;
            #pragma unroll
            for (int i = 0; i < 16; ++i) vpre[i] = vp[(size_t)i * Dn];
        }

        // ---- QK^T (swapped): st[t][j] = S[q=ln][key = kt*64 + 16lg + 4t + j] ----
        f32x4 st[4] = {{0.f,0.f,0.f,0.f},{0.f,0.f,0.f,0.f},{0.f,0.f,0.f,0.f},{0.f,0.f,0.f,0.f}};
        #pragma unroll
        for (int t = 0; t < 4; ++t) {
            const int rr = 16 * t + ln, rsw = (rr & 7) << 4;
            bf16x8 ak0 = *reinterpret_cast<const bf16x8*>(kcur + ((rr * 128 + lg * 16)      ^ rsw));
            st[t] = __builtin_amdgcn_mfma_f32_16x16x32_bf16(ak0, bq0, st[t], 0, 0, 0);
            bf16x8 ak1 = *reinterpret_cast<const bf16x8*>(kcur + ((rr * 128 + lg * 16 + 64) ^ rsw));
            st[t] = __builtin_amdgcn_mfma_f32_16x16x32_bf16(ak1, bq1, st[t], 0, 0, 0);
        }

        // ---- mask (partial last tile only; block-uniform branch) ----
        if (kt * 64 + 64 > valid) {
            #pragma unroll
            for (int t = 0; t < 4; ++t)
                #pragma unroll
                for (int j = 0; j < 4; ++j)
                    if (kt * 64 + 16 * lg + 4 * t + j >= valid) st[t][j] = -1e30f;
        }

        // ---- row max (q=ln): in-register tree + 2 shuffles ----
        float mx;
        {
            float a0 = fmaxf(fmaxf(st[0][0], st[0][1]), fmaxf(st[0][2], st[0][3]));
            float a1 = fmaxf(fmaxf(st[1][0], st[1][1]), fmaxf(st[1][2], st[1][3]));
            float a2 = fmaxf(fmaxf(st[2][0], st[2][1]), fmaxf(st[2][2], st[2][3]));
            float a3 = fmaxf(fmaxf(st[3][0], st[3][1]), fmaxf(st[3][2], st[3][3]));
            mx = fmaxf(fmaxf(a0, a1), fmaxf(a2, a3));
            mx = fmaxf(mx, __shfl_xor(mx, 16, 64));
            mx = fmaxf(mx, __shfl_xor(mx, 32, 64));
        }

        // ---- deferred rescale (T13) ----
        if (__any(mx - mrow > DEFER_THR)) {
            const float mn = fmaxf(mrow, mx);
            const float rs = exp2f(mrow - mn);
            mrow = mn;
            lrow *= rs;
            #pragma unroll
            for (int j = 0; j < 4; ++j) {
                const float rsj = __shfl(rs, lg * 4 + j, 64);  // rescale for q = lg*4+j
                #pragma unroll
                for (int t = 0; t < 4; ++t) acc[t][j] *= rsj;
            }
        }

        // ---- P = exp2(st - mrow): lane's 16 values contiguous -> 2x ds_write_b128 ----
        // st[t][j] -> k^ = 16lg + 4t + j  (element 4t+j of lane segment at k^-base 16lg)
        float rsum = 0.f;
        u16x8 plo, phi;
        #pragma unroll
        for (int t = 0; t < 2; ++t)
            #pragma unroll
            for (int j = 0; j < 4; ++j) {
                const float pv = exp2f(st[t][j] - mrow);   // masked -> 0 exactly
                rsum += pv;
                plo[t * 4 + j] = f2bf(pv);
            }
        #pragma unroll
        for (int t = 2; t < 4; ++t)
            #pragma unroll
            for (int j = 0; j < 4; ++j) {
                const float pv = exp2f(st[t][j] - mrow);
                rsum += pv;
                phi[(t - 2) * 4 + j] = f2bf(pv);
            }
        *reinterpret_cast<u16x8*>(pwb + ((ln * 128 + 32 * lg)      ^ psw)) = plo;
        *reinterpret_cast<u16x8*>(pwb + ((ln * 128 + 32 * lg + 16) ^ psw)) = phi;
        rsum += __shfl_xor(rsum, 16, 64);
        rsum += __shfl_xor(rsum, 32, 64);
        lrow += rsum;
        // plds is per-wave; intra-wave DS order + compiler lgkmcnt protect the reads below.

        // ---- PV: acc[q=lg*4+j][d=16t+ln] += P[16q x 64k^] * V[64k^ x 64d] ----
        #pragma unroll
        for (int s = 0; s < 2; ++s) {
            bf16x8 pa = *reinterpret_cast<const bf16x8*>(pwb + ((ln * 128 + lg * 16 + 64 * s) ^ psw));
            #pragma unroll
            for (int t = 0; t < 4; ++t) {
                const int rr = 16 * t + ln, rsw = (rr & 7) << 4;
                bf16x8 bv = *reinterpret_cast<const bf16x8*>(vcur + ((rr * 128 + lg * 16 + 64 * s) ^ rsw));
                acc[t] = __builtin_amdgcn_mfma_f32_16x16x32_bf16(pa, bv, acc[t], 0, 0, 0);
            }
        }

        // ---- write next tile into the other buffer; single barrier per tile ----
        if (has_next) stage_write(p ^ 1);
        __syncthreads();
    }

    // ---- epilogue: O[q][d] = acc / l ----
    const float invl = 1.0f / lrow;   // for q = ln
    float inv[4];
    #pragma unroll
    for (int j = 0; j < 4; ++j) inv[j] = __shfl(invl, lg * 4 + j, 64);
    float* Orow = O + ((size_t)b * Ln + qbase) * Dn;
    #pragma unroll
    for (int t = 0; t < 4; ++t) {
        #pragma unroll
        for (int j = 0; j < 4; ++j) {
            const int q = lg * 4 + j;
            const int d = 16 * t + ln;
            Orow[(size_t)q * Dn + d] = acc[t][j] * inv[j];
        }
    }
}

extern "C" void kernel_launch(void* const* d_in, const int* in_sizes, int n_in,
                              void* d_out, int out_size, void* d_ws, size_t ws_size,
                              hipStream_t stream) {
    const float* Q = (const float*)d_in[0];
    const float* K = (const float*)d_in[1];
    const float* V = (const float*)d_in[2];
    const int* VL = (const int*)d_in[3];
    float* O = (float*)d_out;
    flash_attn<<<Bn * 16, 256, 0, stream>>>(Q, K, V, VL, O);
}

// Round 11
// 120.719 us; speedup vs baseline: 1.1386x; 1.1386x over previous
//
#include <hip/hip_runtime.h>
#include <math.h>

// Fused flash attention, B=64, L=1024, D=64, fp32 in/out.
// out = softmax(mask(Q K^T / 8)) V ; key >= valid_len[b] -> -1e6 -> exp == 0 exactly,
// so KV tiles >= valid are skipped (exact). exp2 domain, QSCALE folded into Q.
// Swapped-operand QK^T (st = mfma(A=K, B=Q)): lane ln owns q-row ln.
// sigma key-permutation: lane's 16 P-values contiguous -> 2x ds_write_b128.
// Dynamic LPT work queue: 1024 (batch,qtile) items sorted by descending valid,
// 768 persistent blocks pull items via global atomic counter (ws). LDS = 40960
// exactly -> 4 blocks/CU possible, 3/CU used; balance is dynamic, same-batch
// items adjacent in queue -> temporal K/V L2 locality.

typedef __attribute__((ext_vector_type(4))) float f32x4;
typedef __attribute__((ext_vector_type(8))) short bf16x8;
typedef __attribute__((ext_vector_type(8))) unsigned short u16x8;

constexpr int Bn = 64, Ln = 1024, Dn = 64;
constexpr int NITEM = Bn * 16;        // 1024 work items
constexpr int NBLK = 768;             // persistent blocks (3 per CU)
constexpr float QSCALE = 0.125f * 1.44269504088896340736f;  // 1/sqrt(64) * log2(e)
constexpr float DEFER_THR = 10.0f;    // log2 domain: deferred p bounded by 2^10

__device__ inline unsigned short f2bf(float x) {  // round-to-nearest-even
    unsigned int u = __float_as_uint(x);
    return (unsigned short)((u + 0x7fffu + ((u >> 16) & 1u)) >> 16);
}

// setup: LPT order (batches sorted desc by valid) + work counter, in ws
__global__ __launch_bounds__(64) void setup_queue(const int* __restrict__ VL,
                                                  int* __restrict__ ws)
{
    const int l = threadIdx.x;  // 64 threads == 64 batches
    const int vme = VL[l];
    int rank = 0;
    for (int i = 0; i < 64; ++i) {
        const int vi = __shfl(vme, i, 64);
        rank += (vi > vme) || (vi == vme && i < l);
    }
    ws[1 + rank] = l;           // ws[1..64] = order
    if (l == 0) ws[0] = NBLK;   // ws[0] = next unclaimed item
}

__global__ __launch_bounds__(256) void flash_attn(
    const float* __restrict__ Q, const float* __restrict__ K,
    const float* __restrict__ V, const int* __restrict__ VL,
    float* __restrict__ O, int* __restrict__ ws)
{
    __shared__ unsigned short kls[2][64 * 64];   // K tile [sigma(kv)][d] bf16, XOR-swizzled
    __shared__ unsigned short vls[2][64 * 64];   // V tile [d][kv] bf16, XOR-swizzled
    __shared__ unsigned short plds[4][16 * 64];  // per-wave P [q][k^]; [0][0..1] doubles as bcast slot

    const int tid = threadIdx.x;
    const int w = tid >> 6, l = tid & 63;
    const int lg = l >> 4, ln = l & 15;

    const int* ord = ws + 1;
    int* ctr = ws;

    // staging thread mapping (item-independent)
    const int kr = tid >> 2, kc = (tid & 3) * 16;  // K: global row kr, cols kc..kc+15
    const int sr = ((kr & 0xC) << 2) | ((kr >> 2) & 0xC) | (kr & 3);  // sigma(kr)
    const int vd = l, vk0 = w * 16;                // V: d = lane, k = vk0..vk0+15

    char* const kls0 = reinterpret_cast<char*>(kls[0]);
    char* const kls1 = reinterpret_cast<char*>(kls[1]);
    char* const vls0 = reinterpret_cast<char*>(vls[0]);
    char* const vls1 = reinterpret_cast<char*>(vls[1]);
    char* const pwb  = reinterpret_cast<char*>(plds[w]);

    const int kb = sr * 128 + kc * 2, ksw = (sr & 7) << 4;
    const int vb = vd * 128 + vk0 * 2, vsw = (vd & 7) << 4;
    const int psw = (ln & 7) << 4;

    f32x4 kpre[4];
    float vpre[16];

    auto stage_write = [&](int pbuf) {
        char* kd = pbuf ? kls1 : kls0;
        char* vdst = pbuf ? vls1 : vls0;
        u16x8 c0, c1;
        #pragma unroll
        for (int j = 0; j < 4; ++j) {
            c0[j]     = f2bf(kpre[0][j]);  c0[j + 4] = f2bf(kpre[1][j]);
            c1[j]     = f2bf(kpre[2][j]);  c1[j + 4] = f2bf(kpre[3][j]);
        }
        *reinterpret_cast<u16x8*>(kd + ((kb)      ^ ksw)) = c0;
        *reinterpret_cast<u16x8*>(kd + ((kb + 16) ^ ksw)) = c1;
        u16x8 v0, v1;
        #pragma unroll
        for (int j = 0; j < 8; ++j) { v0[j] = f2bf(vpre[j]); v1[j] = f2bf(vpre[j + 8]); }
        *reinterpret_cast<u16x8*>(vdst + ((vb)      ^ vsw)) = v0;
        *reinterpret_cast<u16x8*>(vdst + ((vb + 16) ^ vsw)) = v1;
    };

    int item = blockIdx.x;   // first item: static (LPT order), rest: dynamic

    while (true) {
        const int b = ord[item >> 4];
        const int qt = item & 15;
        const int qbase = qt * 64 + w * 16;
        const int valid = VL[b];
        const int nkt = (valid + 63) >> 6;   // tiles beyond valid contribute exactly 0

        const float* Kbase = K + (size_t)b * Ln * Dn;
        const float* Vbase = V + (size_t)b * Ln * Dn;

        // ---- Q B-fragments (swapped-QK) ----
        bf16x8 bq0, bq1;
        {
            const f32x4* qp = reinterpret_cast<const f32x4*>(Q + ((size_t)b * Ln + qbase + ln) * Dn);
            f32x4 q0 = qp[lg * 2], q1 = qp[lg * 2 + 1], q2 = qp[8 + lg * 2], q3 = qp[8 + lg * 2 + 1];
            #pragma unroll
            for (int j = 0; j < 4; ++j) {
                bq0[j]     = (short)f2bf(q0[j] * QSCALE);
                bq0[j + 4] = (short)f2bf(q1[j] * QSCALE);
                bq1[j]     = (short)f2bf(q2[j] * QSCALE);
                bq1[j + 4] = (short)f2bf(q3[j] * QSCALE);
            }
        }

        // ---- prologue: tile 0 -> buf 0 ----
        {
            const f32x4* kp = reinterpret_cast<const f32x4*>(Kbase + (size_t)kr * Dn + kc);
            #pragma unroll
            for (int i = 0; i < 4; ++i) kpre[i] = kp[i];
            const float* vp = Vbase + (size_t)vk0 * Dn + vd;
            #pragma unroll
            for (int i = 0; i < 16; ++i) vpre[i] = vp[(size_t)i * Dn];
        }
        stage_write(0);
        __syncthreads();

        f32x4 acc[4] = {{0.f,0.f,0.f,0.f},{0.f,0.f,0.f,0.f},{0.f,0.f,0.f,0.f},{0.f,0.f,0.f,0.f}};
        float mrow = -1e30f;   // running max for q = ln (replicated over 4 lane-groups)
        float lrow = 0.f;

        int p = 0;
        for (int kt = 0; kt < nkt; ++kt, p ^= 1) {
            const bool has_next = (kt + 1 < nkt);
            char* kcur = p ? kls1 : kls0;
            char* vcur = p ? vls1 : vls0;

            // ---- issue next tile's global loads (consumed by stage_write below) ----
            if (has_next) {
                const f32x4* kp = reinterpret_cast<const f32x4*>(Kbase + (size_t)((kt + 1) * 64 + kr) * Dn + kc);
                #pragma unroll
                for (int i = 0; i < 4; ++i) kpre[i] = kp[i];
                const float* vp = Vbase + (size_t)((kt + 1) * 64 + vk0) * Dn + vd;
                #pragma unroll
                for (int i = 0; i < 16; ++i) vpre[i] = vp[(size_t)i * Dn];
            }

            // ---- QK^T (swapped): st[t][j] = S[q=ln][key = kt*64 + 16lg + 4t + j] ----
            f32x4 st[4] = {{0.f,0.f,0.f,0.f},{0.f,0.f,0.f,0.f},{0.f,0.f,0.f,0.f},{0.f,0.f,0.f,0.f}};
            #pragma unroll
            for (int t = 0; t < 4; ++t) {
                const int rr = 16 * t + ln, rsw = (rr & 7) << 4;
                bf16x8 ak0 = *reinterpret_cast<const bf16x8*>(kcur + ((rr * 128 + lg * 16)      ^ rsw));
                st[t] = __builtin_amdgcn_mfma_f32_16x16x32_bf16(ak0, bq0, st[t], 0, 0, 0);
                bf16x8 ak1 = *reinterpret_cast<const bf16x8*>(kcur + ((rr * 128 + lg * 16 + 64) ^ rsw));
                st[t] = __builtin_amdgcn_mfma_f32_16x16x32_bf16(ak1, bq1, st[t], 0, 0, 0);
            }

            // ---- mask (partial last tile only; block-uniform branch) ----
            if (kt * 64 + 64 > valid) {
                #pragma unroll
                for (int t = 0; t < 4; ++t)
                    #pragma unroll
                    for (int j = 0; j < 4; ++j)
                        if (kt * 64 + 16 * lg + 4 * t + j >= valid) st[t][j] = -1e30f;
            }

            // ---- row max (q=ln): in-register tree + 2 shuffles ----
            float mx;
            {
                float a0 = fmaxf(fmaxf(st[0][0], st[0][1]), fmaxf(st[0][2], st[0][3]));
                float a1 = fmaxf(fmaxf(st[1][0], st[1][1]), fmaxf(st[1][2], st[1][3]));
                float a2 = fmaxf(fmaxf(st[2][0], st[2][1]), fmaxf(st[2][2], st[2][3]));
                float a3 = fmaxf(fmaxf(st[3][0], st[3][1]), fmaxf(st[3][2], st[3][3]));
                mx = fmaxf(fmaxf(a0, a1), fmaxf(a2, a3));
                mx = fmaxf(mx, __shfl_xor(mx, 16, 64));
                mx = fmaxf(mx, __shfl_xor(mx, 32, 64));
            }

            // ---- deferred rescale (T13) ----
            if (__any(mx - mrow > DEFER_THR)) {
                const float mn = fmaxf(mrow, mx);
                const float rs = exp2f(mrow - mn);
                mrow = mn;
                lrow *= rs;
                #pragma unroll
                for (int j = 0; j < 4; ++j) {
                    const float rsj = __shfl(rs, lg * 4 + j, 64);
                    #pragma unroll
                    for (int t = 0; t < 4; ++t) acc[t][j] *= rsj;
                }
            }

            // ---- P = exp2(st - mrow): lane's 16 values contiguous -> 2x ds_write_b128 ----
            float rsum = 0.f;
            u16x8 plo, phi;
            #pragma unroll
            for (int t = 0; t < 2; ++t)
                #pragma unroll
                for (int j = 0; j < 4; ++j) {
                    const float pv = exp2f(st[t][j] - mrow);   // masked -> 0 exactly
                    rsum += pv;
                    plo[t * 4 + j] = f2bf(pv);
                }
            #pragma unroll
            for (int t = 2; t < 4; ++t)
                #pragma unroll
                for (int j = 0; j < 4; ++j) {
                    const float pv = exp2f(st[t][j] - mrow);
                    rsum += pv;
                    phi[(t - 2) * 4 + j] = f2bf(pv);
                }
            *reinterpret_cast<u16x8*>(pwb + ((ln * 128 + 32 * lg)      ^ psw)) = plo;
            *reinterpret_cast<u16x8*>(pwb + ((ln * 128 + 32 * lg + 16) ^ psw)) = phi;
            rsum += __shfl_xor(rsum, 16, 64);
            rsum += __shfl_xor(rsum, 32, 64);
            lrow += rsum;

            // ---- PV: acc[q=lg*4+j][d=16t+ln] += P[16q x 64k^] * V[64k^ x 64d] ----
            #pragma unroll
            for (int s = 0; s < 2; ++s) {
                bf16x8 pa = *reinterpret_cast<const bf16x8*>(pwb + ((ln * 128 + lg * 16 + 64 * s) ^ psw));
                #pragma unroll
                for (int t = 0; t < 4; ++t) {
                    const int rr = 16 * t + ln, rsw = (rr & 7) << 4;
                    bf16x8 bv = *reinterpret_cast<const bf16x8*>(vcur + ((rr * 128 + lg * 16 + 64 * s) ^ rsw));
                    acc[t] = __builtin_amdgcn_mfma_f32_16x16x32_bf16(pa, bv, acc[t], 0, 0, 0);
                }
            }

            // ---- write next tile into the other buffer; single barrier per tile ----
            if (has_next) stage_write(p ^ 1);
            __syncthreads();
        }

        // ---- epilogue: O[q][d] = acc / l (no LDS) ----
        const float invl = 1.0f / lrow;
        float inv[4];
        #pragma unroll
        for (int j = 0; j < 4; ++j) inv[j] = __shfl(invl, lg * 4 + j, 64);
        float* Orow = O + ((size_t)b * Ln + qbase) * Dn;
        #pragma unroll
        for (int t = 0; t < 4; ++t) {
            #pragma unroll
            for (int j = 0; j < 4; ++j) {
                const int q = lg * 4 + j;
                const int d = 16 * t + ln;
                Orow[(size_t)q * Dn + d] = acc[t][j] * inv[j];
            }
        }

        // ---- pull next item (one atomic per block, broadcast via plds scratch) ----
        // Last kt-iteration's __syncthreads ordered all plds reads before here.
        if (tid == 0) *reinterpret_cast<int*>(&plds[0][0]) = atomicAdd(ctr, 1);
        __syncthreads();
        item = *reinterpret_cast<const int*>(&plds[0][0]);
        if (item >= NITEM) break;
        __syncthreads();   // keep bcast slot stable until all waves consumed it
    }
}

extern "C" void kernel_launch(void* const* d_in, const int* in_sizes, int n_in,
                              void* d_out, int out_size, void* d_ws, size_t ws_size,
                              hipStream_t stream) {
    const float* Q = (const float*)d_in[0];
    const float* K = (const float*)d_in[1];
    const float* V = (const float*)d_in[2];
    const int* VL = (const int*)d_in[3];
    float* O = (float*)d_out;
    int* ws = (int*)d_ws;

    setup_queue<<<1, 64, 0, stream>>>(VL, ws);
    flash_attn<<<NBLK, 256, 0, stream>>>(Q, K, V, VL, O, ws);
}

// Round 12
// 117.557 us; speedup vs baseline: 1.1693x; 1.0269x over previous
//
#include <hip/hip_runtime.h>
#include <math.h>

// Fused flash attention, B=64, L=1024, D=64, fp32 in/out.
// out = softmax(mask(Q K^T / 8)) V ; key >= valid_len[b] -> -1e6 -> exp == 0 exactly,
// so KV tiles >= valid are skipped (exact). exp2 domain, QSCALE folded into Q.
// Swapped-operand QK^T (st = mfma(A=K, B=Q)): lane ln owns q-row ln.
// sigma key-permutation r={k5,k2,k4,k3,k1,k0}: st[t][j] = key 32(t>>1)+8lg+4(t&1)+j
// == PV A-frag element layout -> P stays ENTIRELY in registers (no P LDS).
// All f32->bf16 via v_cvt_pk_bf16_f32 (2 vals/instr, RNE).
// Dynamic LPT work queue: 1024 (batch,qtile) items desc-sorted by valid, 768
// persistent blocks pull via atomic counter in ws; same-batch items adjacent.

typedef __attribute__((ext_vector_type(4))) float f32x4;
typedef __attribute__((ext_vector_type(8))) short bf16x8;
typedef __attribute__((ext_vector_type(4))) unsigned int u32x4;

constexpr int Bn = 64, Ln = 1024, Dn = 64;
constexpr int NITEM = Bn * 16;        // 1024 work items
constexpr int NBLK = 768;             // persistent blocks (3 per CU)
constexpr float QSCALE = 0.125f * 1.44269504088896340736f;  // 1/sqrt(64) * log2(e)
constexpr float DEFER_THR = 10.0f;    // log2 domain: deferred p bounded by 2^10

__device__ inline unsigned int cvt_pk(float lo, float hi) {  // 2x f32 -> packed bf16, RNE
    unsigned int r;
    asm("v_cvt_pk_bf16_f32 %0, %1, %2" : "=v"(r) : "v"(lo), "v"(hi));
    return r;
}

// setup: LPT order (batches sorted desc by valid) + work counter, in ws
__global__ __launch_bounds__(64) void setup_queue(const int* __restrict__ VL,
                                                  int* __restrict__ ws)
{
    const int l = threadIdx.x;  // 64 threads == 64 batches
    const int vme = VL[l];
    int rank = 0;
    for (int i = 0; i < 64; ++i) {
        const int vi = __shfl(vme, i, 64);
        rank += (vi > vme) || (vi == vme && i < l);
    }
    ws[1 + rank] = l;           // ws[1..64] = order
    if (l == 0) ws[0] = NBLK;   // ws[0] = next unclaimed item
}

__global__ __launch_bounds__(256) void flash_attn(
    const float* __restrict__ Q, const float* __restrict__ K,
    const float* __restrict__ V, const int* __restrict__ VL,
    float* __restrict__ O, int* __restrict__ ws)
{
    __shared__ unsigned short kls[2][64 * 64];   // K tile [sigma(kv)][d] bf16, XOR-swizzled
    __shared__ unsigned short vls[2][64 * 64];   // V tile [d][kv] bf16, XOR-swizzled
    __shared__ int bcast;                        // work-item broadcast

    const int tid = threadIdx.x;
    const int w = tid >> 6, l = tid & 63;
    const int lg = l >> 4, ln = l & 15;

    const int* ord = ws + 1;
    int* ctr = ws;

    // staging thread mapping (item-independent)
    const int kr = tid >> 2, kc = (tid & 3) * 16;  // K: global key kr, cols kc..kc+15
    // sigma: r = {k5, k2, k4, k3, k1, k0}
    const int sr = (kr & 0x23) | ((kr & 0x04) << 2) | ((kr & 0x18) >> 1);
    const int vd = l, vk0 = w * 16;                // V: d = lane, k = vk0..vk0+15

    char* const kls0 = reinterpret_cast<char*>(kls[0]);
    char* const kls1 = reinterpret_cast<char*>(kls[1]);
    char* const vls0 = reinterpret_cast<char*>(vls[0]);
    char* const vls1 = reinterpret_cast<char*>(vls[1]);

    const int kb = sr * 128 + kc * 2, ksw = (sr & 7) << 4;
    const int vb = vd * 128 + vk0 * 2, vsw = (vd & 7) << 4;

    f32x4 kpre[4];
    float vpre[16];

    auto stage_write = [&](int pbuf) {
        char* kd = pbuf ? kls1 : kls0;
        char* vdst = pbuf ? vls1 : vls0;
        u32x4 c;
        c[0] = cvt_pk(kpre[0][0], kpre[0][1]);
        c[1] = cvt_pk(kpre[0][2], kpre[0][3]);
        c[2] = cvt_pk(kpre[1][0], kpre[1][1]);
        c[3] = cvt_pk(kpre[1][2], kpre[1][3]);
        *reinterpret_cast<u32x4*>(kd + ((kb)      ^ ksw)) = c;
        c[0] = cvt_pk(kpre[2][0], kpre[2][1]);
        c[1] = cvt_pk(kpre[2][2], kpre[2][3]);
        c[2] = cvt_pk(kpre[3][0], kpre[3][1]);
        c[3] = cvt_pk(kpre[3][2], kpre[3][3]);
        *reinterpret_cast<u32x4*>(kd + ((kb + 16) ^ ksw)) = c;
        c[0] = cvt_pk(vpre[0],  vpre[1]);
        c[1] = cvt_pk(vpre[2],  vpre[3]);
        c[2] = cvt_pk(vpre[4],  vpre[5]);
        c[3] = cvt_pk(vpre[6],  vpre[7]);
        *reinterpret_cast<u32x4*>(vdst + ((vb)      ^ vsw)) = c;
        c[0] = cvt_pk(vpre[8],  vpre[9]);
        c[1] = cvt_pk(vpre[10], vpre[11]);
        c[2] = cvt_pk(vpre[12], vpre[13]);
        c[3] = cvt_pk(vpre[14], vpre[15]);
        *reinterpret_cast<u32x4*>(vdst + ((vb + 16) ^ vsw)) = c;
    };

    int item = blockIdx.x;   // first item: static (LPT order), rest: dynamic

    while (true) {
        const int b = ord[item >> 4];
        const int qt = item & 15;
        const int qbase = qt * 64 + w * 16;
        const int valid = VL[b];
        const int nkt = (valid + 63) >> 6;   // tiles beyond valid contribute exactly 0

        const float* Kbase = K + (size_t)b * Ln * Dn;
        const float* Vbase = V + (size_t)b * Ln * Dn;

        // ---- Q B-fragments (swapped-QK): lane holds Q[q=ln][d=8lg+e] ----
        bf16x8 bq0, bq1;
        {
            const f32x4* qp = reinterpret_cast<const f32x4*>(Q + ((size_t)b * Ln + qbase + ln) * Dn);
            f32x4 q0 = qp[lg * 2], q1 = qp[lg * 2 + 1], q2 = qp[8 + lg * 2], q3 = qp[8 + lg * 2 + 1];
            u32x4 c;
            c[0] = cvt_pk(q0[0] * QSCALE, q0[1] * QSCALE);
            c[1] = cvt_pk(q0[2] * QSCALE, q0[3] * QSCALE);
            c[2] = cvt_pk(q1[0] * QSCALE, q1[1] * QSCALE);
            c[3] = cvt_pk(q1[2] * QSCALE, q1[3] * QSCALE);
            bq0 = reinterpret_cast<bf16x8&>(c);
            u32x4 d;
            d[0] = cvt_pk(q2[0] * QSCALE, q2[1] * QSCALE);
            d[1] = cvt_pk(q2[2] * QSCALE, q2[3] * QSCALE);
            d[2] = cvt_pk(q3[0] * QSCALE, q3[1] * QSCALE);
            d[3] = cvt_pk(q3[2] * QSCALE, q3[3] * QSCALE);
            bq1 = reinterpret_cast<bf16x8&>(d);
        }

        // ---- prologue: tile 0 -> buf 0 ----
        {
            const f32x4* kp = reinterpret_cast<const f32x4*>(Kbase + (size_t)kr * Dn + kc);
            #pragma unroll
            for (int i = 0; i < 4; ++i) kpre[i] = kp[i];
            const float* vp = Vbase + (size_t)vk0 * Dn + vd;
            #pragma unroll
            for (int i = 0; i < 16; ++i) vpre[i] = vp[(size_t)i * Dn];
        }
        stage_write(0);
        __syncthreads();

        f32x4 acc[4] = {{0.f,0.f,0.f,0.f},{0.f,0.f,0.f,0.f},{0.f,0.f,0.f,0.f},{0.f,0.f,0.f,0.f}};
        float mrow = -1e30f;   // running max for q = ln (replicated over 4 lane-groups)
        float lrow = 0.f;

        int p = 0;
        for (int kt = 0; kt < nkt; ++kt, p ^= 1) {
            const bool has_next = (kt + 1 < nkt);
            char* kcur = p ? kls1 : kls0;
            char* vcur = p ? vls1 : vls0;

            // ---- issue next tile's global loads (consumed by stage_write below) ----
            if (has_next) {
                const f32x4* kp = reinterpret_cast<const f32x4*>(Kbase + (size_t)((kt + 1) * 64 + kr) * Dn + kc);
                #pragma unroll
                for (int i = 0; i < 4; ++i) kpre[i] = kp[i];
                const float* vp = Vbase + (size_t)((kt + 1) * 64 + vk0) * Dn + vd;
                #pragma unroll
                for (int i = 0; i < 16; ++i) vpre[i] = vp[(size_t)i * Dn];
            }

            // ---- QK^T (swapped): st[t][j] = S[q=ln][key = kt*64 + 32(t>>1)+8lg+4(t&1)+j] ----
            f32x4 st[4] = {{0.f,0.f,0.f,0.f},{0.f,0.f,0.f,0.f},{0.f,0.f,0.f,0.f},{0.f,0.f,0.f,0.f}};
            __builtin_amdgcn_s_setprio(1);
            #pragma unroll
            for (int t = 0; t < 4; ++t) {
                const int rr = 16 * t + ln, rsw = (rr & 7) << 4;
                bf16x8 ak0 = *reinterpret_cast<const bf16x8*>(kcur + ((rr * 128 + lg * 16)      ^ rsw));
                st[t] = __builtin_amdgcn_mfma_f32_16x16x32_bf16(ak0, bq0, st[t], 0, 0, 0);
                bf16x8 ak1 = *reinterpret_cast<const bf16x8*>(kcur + ((rr * 128 + lg * 16 + 64) ^ rsw));
                st[t] = __builtin_amdgcn_mfma_f32_16x16x32_bf16(ak1, bq1, st[t], 0, 0, 0);
            }
            __builtin_amdgcn_s_setprio(0);

            // ---- mask (partial last tile only; block-uniform branch) ----
            if (kt * 64 + 64 > valid) {
                #pragma unroll
                for (int t = 0; t < 4; ++t)
                    #pragma unroll
                    for (int j = 0; j < 4; ++j)
                        if (kt * 64 + 32 * (t >> 1) + 8 * lg + 4 * (t & 1) + j >= valid)
                            st[t][j] = -1e30f;
            }

            // ---- row max (q=ln): in-register tree + 2 shuffles ----
            float mx;
            {
                float a0 = fmaxf(fmaxf(st[0][0], st[0][1]), fmaxf(st[0][2], st[0][3]));
                float a1 = fmaxf(fmaxf(st[1][0], st[1][1]), fmaxf(st[1][2], st[1][3]));
                float a2 = fmaxf(fmaxf(st[2][0], st[2][1]), fmaxf(st[2][2], st[2][3]));
                float a3 = fmaxf(fmaxf(st[3][0], st[3][1]), fmaxf(st[3][2], st[3][3]));
                mx = fmaxf(fmaxf(a0, a1), fmaxf(a2, a3));
                mx = fmaxf(mx, __shfl_xor(mx, 16, 64));
                mx = fmaxf(mx, __shfl_xor(mx, 32, 64));
            }

            // ---- deferred rescale (T13) ----
            if (__any(mx - mrow > DEFER_THR)) {
                const float mn = fmaxf(mrow, mx);
                const float rs = exp2f(mrow - mn);
                mrow = mn;
                lrow *= rs;
                #pragma unroll
                for (int j = 0; j < 4; ++j) {
                    const float rsj = __shfl(rs, lg * 4 + j, 64);
                    #pragma unroll
                    for (int t = 0; t < 4; ++t) acc[t][j] *= rsj;
                }
            }

            // ---- P = exp2(st - mrow), packed in-register as PV A-frags ----
            float pv[4][4];
            float rsum = 0.f;
            #pragma unroll
            for (int t = 0; t < 4; ++t)
                #pragma unroll
                for (int j = 0; j < 4; ++j) {
                    pv[t][j] = exp2f(st[t][j] - mrow);   // masked -> 0 exactly
                    rsum += pv[t][j];
                }
            u32x4 w0, w1;
            w0[0] = cvt_pk(pv[0][0], pv[0][1]);  w0[1] = cvt_pk(pv[0][2], pv[0][3]);
            w0[2] = cvt_pk(pv[1][0], pv[1][1]);  w0[3] = cvt_pk(pv[1][2], pv[1][3]);
            w1[0] = cvt_pk(pv[2][0], pv[2][1]);  w1[1] = cvt_pk(pv[2][2], pv[2][3]);
            w1[2] = cvt_pk(pv[3][0], pv[3][1]);  w1[3] = cvt_pk(pv[3][2], pv[3][3]);
            bf16x8 pa0 = reinterpret_cast<bf16x8&>(w0);   // kdim 8lg+e, s=0
            bf16x8 pa1 = reinterpret_cast<bf16x8&>(w1);   // kdim 8lg+e, s=1
            rsum += __shfl_xor(rsum, 16, 64);
            rsum += __shfl_xor(rsum, 32, 64);
            lrow += rsum;

            // ---- PV: acc[q=lg*4+j][d=16t+ln] += P[16q x 64k] * V[64k x 64d] ----
            __builtin_amdgcn_s_setprio(1);
            #pragma unroll
            for (int t = 0; t < 4; ++t) {
                const int rr = 16 * t + ln, rsw = (rr & 7) << 4;
                bf16x8 bv0 = *reinterpret_cast<const bf16x8*>(vcur + ((rr * 128 + lg * 16)      ^ rsw));
                acc[t] = __builtin_amdgcn_mfma_f32_16x16x32_bf16(pa0, bv0, acc[t], 0, 0, 0);
                bf16x8 bv1 = *reinterpret_cast<const bf16x8*>(vcur + ((rr * 128 + lg * 16 + 64) ^ rsw));
                acc[t] = __builtin_amdgcn_mfma_f32_16x16x32_bf16(pa1, bv1, acc[t], 0, 0, 0);
            }
            __builtin_amdgcn_s_setprio(0);

            // ---- write next tile into the other buffer; single barrier per tile ----
            if (has_next) stage_write(p ^ 1);
            __syncthreads();
        }

        // ---- epilogue: O[q][d] = acc / l ----
        const float invl = 1.0f / lrow;
        float inv[4];
        #pragma unroll
        for (int j = 0; j < 4; ++j) inv[j] = __shfl(invl, lg * 4 + j, 64);
        float* Orow = O + ((size_t)b * Ln + qbase) * Dn;
        #pragma unroll
        for (int t = 0; t < 4; ++t) {
            #pragma unroll
            for (int j = 0; j < 4; ++j) {
                const int q = lg * 4 + j;
                const int d = 16 * t + ln;
                Orow[(size_t)q * Dn + d] = acc[t][j] * inv[j];
            }
        }

        // ---- pull next item (one atomic per block) ----
        if (tid == 0) bcast = atomicAdd(ctr, 1);
        __syncthreads();
        item = bcast;
        if (item >= NITEM) break;
        __syncthreads();   // keep bcast stable until all waves consumed it
    }
}

extern "C" void kernel_launch(void* const* d_in, const int* in_sizes, int n_in,
                              void* d_out, int out_size, void* d_ws, size_t ws_size,
                              hipStream_t stream) {
    const float* Q = (const float*)d_in[0];
    const float* K = (const float*)d_in[1];
    const float* V = (const float*)d_in[2];
    const int* VL = (const int*)d_in[3];
    float* O = (float*)d_out;
    int* ws = (int*)d_ws;

    setup_queue<<<1, 64, 0, stream>>>(VL, ws);
    flash_attn<<<NBLK, 256, 0, stream>>>(Q, K, V, VL, O, ws);
}